// Round 2
// baseline (264.664 us; speedup 1.0000x reference)
//
#include <hip/hip_runtime.h>

// Problem: out[b, I[e]] += inputs[b, J[e]] * W3[e] * velocity[J[e]]; out += bias
// Layout strategy: B == 64 == wavefront size. Work in [N, B] (transposed) space so
// each edge is one wave-coalesced 256B load + one wave-coalesced 256B atomicAdd.

#define BATCH 64

// ---- transpose inputs [B,N] -> in_T [N,B] (LDS tiled, +1 pad) ----
__global__ void k_transpose_in(const float* __restrict__ in, float* __restrict__ in_T, int N) {
    __shared__ float tile[64 * 65];
    const int n0 = blockIdx.x * 64;
    const int t  = threadIdx.x;      // 256 threads
    const int x  = t & 63;
    const int r  = t >> 6;           // 0..3
    // load: coalesced along n for each batch row
    for (int b = r; b < BATCH; b += 4) {
        float v = 0.f;
        if (n0 + x < N) v = in[(size_t)b * N + n0 + x];
        tile[x * 65 + b] = v;
    }
    __syncthreads();
    // store: coalesced along b
    for (int xr = r; xr < 64; xr += 4) {
        if (n0 + xr < N) in_T[(size_t)(n0 + xr) * BATCH + x] = tile[xr * 65 + x];
    }
}

// ---- edge scatter: one wave per 64-edge chunk ----
__global__ void k_edge_scatter(const float* __restrict__ in_T,
                               const float* __restrict__ W3,
                               const float* __restrict__ velocity,
                               const int* __restrict__ I,
                               const int* __restrict__ J,
                               float* __restrict__ out_T, int E) {
    const int lane = threadIdx.x & 63;
    const long wave   = (long)blockIdx.x * (blockDim.x >> 6) + (threadIdx.x >> 6);
    const long nwaves = (long)gridDim.x * (blockDim.x >> 6);

    for (long base = wave * 64; base < E; base += nwaves * 64) {
        // coalesced prefetch of 64 edges' metadata
        const long e = base + lane;
        int   iv = 0, jv = 0;
        float wvv = 0.f;
        if (e < E) {
            iv  = I[e];
            jv  = J[e];
            wvv = W3[e] * velocity[jv];
        }
        const int cnt = (int)((E - base) < 64 ? (E - base) : 64);
        for (int k = 0; k < cnt; ++k) {
            const int   ii = __shfl(iv, k);
            const int   jj = __shfl(jv, k);
            const float wv = __shfl(wvv, k);
            const float val = in_T[(size_t)jj * BATCH + lane] * wv;
            atomicAdd(&out_T[(size_t)ii * BATCH + lane], val);
        }
    }
}

// ---- transpose out_T [N,B] -> out [B,N], add bias ----
__global__ void k_transpose_out(const float* __restrict__ out_T,
                                const float* __restrict__ bias,
                                float* __restrict__ out, int N) {
    __shared__ float tile[64 * 65];
    const int n0 = blockIdx.x * 64;
    const int t  = threadIdx.x;
    const int x  = t & 63;
    const int r  = t >> 6;
    for (int xr = r; xr < 64; xr += 4) {
        float v = 0.f;
        if (n0 + xr < N) v = out_T[(size_t)(n0 + xr) * BATCH + x];
        tile[xr * 65 + x] = v;
    }
    __syncthreads();
    for (int b = r; b < BATCH; b += 4) {
        const int n = n0 + x;
        if (n < N) out[(size_t)b * N + n] = tile[x * 65 + b] + bias[n];
    }
}

// ---- fallback path (ws too small): direct atomics into d_out ----
__global__ void k_edge_scatter_direct(const float* __restrict__ in,
                                      const float* __restrict__ W3,
                                      const float* __restrict__ velocity,
                                      const int* __restrict__ I,
                                      const int* __restrict__ J,
                                      float* __restrict__ out, int N, int E) {
    const int lane = threadIdx.x & 63;   // lane = batch index
    const long wave   = (long)blockIdx.x * (blockDim.x >> 6) + (threadIdx.x >> 6);
    const long nwaves = (long)gridDim.x * (blockDim.x >> 6);
    for (long base = wave * 64; base < E; base += nwaves * 64) {
        const long e = base + lane;
        int iv = 0, jv = 0; float wvv = 0.f;
        if (e < E) { iv = I[e]; jv = J[e]; wvv = W3[e] * velocity[jv]; }
        const int cnt = (int)((E - base) < 64 ? (E - base) : 64);
        for (int k = 0; k < cnt; ++k) {
            const int   ii = __shfl(iv, k);
            const int   jj = __shfl(jv, k);
            const float wv = __shfl(wvv, k);
            const float val = in[(size_t)lane * N + jj] * wv;
            atomicAdd(&out[(size_t)lane * N + ii], val);
        }
    }
}

__global__ void k_add_bias(const float* __restrict__ bias, float* __restrict__ out, int N, int total) {
    int idx = blockIdx.x * blockDim.x + threadIdx.x;
    if (idx < total) out[idx] += bias[idx % N];
}

extern "C" void kernel_launch(void* const* d_in, const int* in_sizes, int n_in,
                              void* d_out, int out_size, void* d_ws, size_t ws_size,
                              hipStream_t stream) {
    const float* inputs   = (const float*)d_in[0];
    const float* W3       = (const float*)d_in[1];
    const float* bias     = (const float*)d_in[2];
    const float* velocity = (const float*)d_in[3];
    const int*   I        = (const int*)d_in[4];
    const int*   J        = (const int*)d_in[5];
    const int E = in_sizes[1];
    const int N = in_sizes[3];
    float* out = (float*)d_out;

    const size_t mat_elems = (size_t)N * BATCH;
    const size_t need = 2 * mat_elems * sizeof(float);

    const int waves_needed  = (E + 63) / 64;           // one wave per 64-edge chunk
    const int scatter_blocks = (waves_needed + 3) / 4; // 4 waves / 256-thread block

    if (ws_size >= need) {
        float* in_T  = (float*)d_ws;
        float* out_T = in_T + mat_elems;
        const int nb = (N + 63) / 64;

        k_transpose_in<<<nb, 256, 0, stream>>>(inputs, in_T, N);
        hipMemsetAsync(out_T, 0, mat_elems * sizeof(float), stream);
        k_edge_scatter<<<scatter_blocks, 256, 0, stream>>>(in_T, W3, velocity, I, J, out_T, E);
        k_transpose_out<<<nb, 256, 0, stream>>>(out_T, bias, out, N);
    } else {
        hipMemsetAsync(out, 0, (size_t)out_size * sizeof(float), stream);
        k_edge_scatter_direct<<<scatter_blocks, 256, 0, stream>>>(inputs, W3, velocity, I, J, out, N, E);
        const int total = out_size;
        k_add_bias<<<(total + 255) / 256, 256, 0, stream>>>(bias, out, N, total);
    }
}